// Round 1
// 559.412 us; speedup vs baseline: 1.1195x; 1.1195x over previous
//
#include <hip/hip_runtime.h>
#include <hip/hip_bf16.h>
#include <math.h>

#define N_NODES 100000
#define N_EDGES 1600000
#define F_IN 512
#define F_GNN 128
#define HID 64
#define Z_DIM 64
#define N_GRAPHS 512
#define N_REGIONS 196      // 512 nodes per region
#define REGION_CAP 10240   // mean 8163, sd ~90 -> +22 sigma

typedef __attribute__((ext_vector_type(8))) short short8;
typedef __attribute__((ext_vector_type(4))) float f32x4;

// ---------- small device helpers ----------
__device__ __forceinline__ float eluf(float v) { return v > 0.f ? v : expm1f(v); }
__device__ __forceinline__ float softplusf(float v) {
  return fmaxf(v, 0.f) + log1pf(expf(-fabsf(v)));
}
__device__ __forceinline__ float sigmoidf(float v) { return 1.f / (1.f + expf(-v)); }

__device__ __forceinline__ unsigned short f2bf(float f) {
  unsigned int u = __float_as_uint(f);
  u = (u + 0x7fffu + ((u >> 16) & 1u)) >> 16;
  return (unsigned short)u;
}
// packed f32x2 -> bf16x2 (low = a, high = b)
__device__ __forceinline__ unsigned int f2bf2(float a, float b) {
  __hip_bfloat162 h = __float22bfloat162_rn(make_float2(a, b));
  unsigned int u;
  __builtin_memcpy(&u, &h, 4);
  return u;
}
__device__ __forceinline__ float bf_lo(unsigned int u) { return __uint_as_float(u << 16); }
__device__ __forceinline__ float bf_hi(unsigned int u) { return __uint_as_float(u & 0xffff0000u); }

__device__ __forceinline__ int lower_bound_i(const int* __restrict__ a, int n, int v) {
  int lo = 0, hi = n;
  while (lo < hi) {
    int mid = (lo + hi) >> 1;
    if (a[mid] < v) lo = mid + 1; else hi = mid;
  }
  return lo;
}

// ---------- Wg -> WgT bf16 (B^T layout: [n][k]); block 0 also zeroes region counters ----------
__global__ void k_wg(const float* __restrict__ Wg, unsigned short* __restrict__ WgT,
                     int* __restrict__ rcnt) {
  int i = blockIdx.x * 256 + threadIdx.x;   // 65536 total
  if (blockIdx.x == 0) rcnt[threadIdx.x] = 0;
  int n = i >> 9, k = i & 511;
  WgT[i] = f2bf(Wg[k * F_GNN + n]);
}

// ---------- region counts (196 counters), LDS-staged ----------
__global__ __launch_bounds__(256) void k_rcount(const int* __restrict__ ei,
                                                int* __restrict__ rcnt) {
  __shared__ int lh[256];
  const int b = blockIdx.x, t = threadIdx.x;
  lh[t] = 0;
  __syncthreads();
#pragma unroll
  for (int j = 0; j < 8; j++) {
    int e = b * 2048 + t + 256 * j;
    if (e < N_EDGES) atomicAdd(&lh[ei[N_EDGES + e] >> 9], 1);
  }
  __syncthreads();
  if (t < N_REGIONS && lh[t] > 0) atomicAdd(&rcnt[t], lh[t]);
}

// ---------- scan 196 region counts -> rbase (excl) + seed cursors ----------
__global__ __launch_bounds__(256) void k_rscan(int* __restrict__ rcnt,  // == cursor_r
                                               int* __restrict__ rbase) {
  __shared__ int s[256];
  int t = threadIdx.x;
  s[t] = (t < N_REGIONS) ? rcnt[t] : 0;
  __syncthreads();
#pragma unroll
  for (int d = 1; d < 256; d <<= 1) {
    int v = (t >= d) ? s[t - d] : 0;
    __syncthreads();
    s[t] += v;
    __syncthreads();
  }
  int excl = (t > 0) ? s[t - 1] : 0;
  rbase[t] = excl;
  rcnt[t] = excl;               // cursor seed
  if (t == 255) rbase[N_REGIONS] = s[255];   // = N_EDGES
}

// ---------- pass 1: bucket edges into 196 regions, LDS-staged ----------
__global__ __launch_bounds__(256) void k_bucket(
    const int* __restrict__ ei, int* __restrict__ cursor_r,
    uint2* __restrict__ pairs) {
  __shared__ int lhist[256];
  __shared__ int lofs[256];
  __shared__ int lcur[256];
  __shared__ int gbase[256];
  __shared__ int sc[256];
  __shared__ uint2 lpairs[4096];   // 32 KB

  const int b = blockIdx.x, t = threadIdx.x;
  const int e0 = b * 4096;
  const int n_b = min(4096, N_EDGES - e0);

  lhist[t] = 0;
  lcur[t] = 0;
  __syncthreads();

  int srcv[16], dstv[16];
#pragma unroll
  for (int j = 0; j < 16; j++) {
    int e = e0 + t + 256 * j;
    if (e < N_EDGES) {
      srcv[j] = ei[e];
      dstv[j] = ei[N_EDGES + e];
      atomicAdd(&lhist[dstv[j] >> 9], 1);
    } else {
      dstv[j] = -1;
    }
  }
  __syncthreads();

  // exclusive scan of lhist -> lofs
  sc[t] = lhist[t];
  __syncthreads();
#pragma unroll
  for (int d = 1; d < 256; d <<= 1) {
    int v = (t >= d) ? sc[t - d] : 0;
    __syncthreads();
    sc[t] += v;
    __syncthreads();
  }
  lofs[t] = (t > 0) ? sc[t - 1] : 0;
  // global base per region
  if (t < N_REGIONS && lhist[t] > 0) gbase[t] = atomicAdd(&cursor_r[t], lhist[t]);
  __syncthreads();

  // local scatter into LDS, region-contiguous
#pragma unroll
  for (int j = 0; j < 16; j++) {
    if (dstv[j] >= 0) {
      int r = dstv[j] >> 9;
      int pos = lofs[r] + atomicAdd(&lcur[r], 1);
      lpairs[pos] = make_uint2((unsigned)srcv[j], (unsigned)dstv[j]);
    }
  }
  __syncthreads();

  // flush: consecutive i -> consecutive slot within region run (coalesced)
  for (int i = t; i < n_b; i += 256) {
    int lo = 0, hi = N_REGIONS;
    while (hi - lo > 1) {
      int mid = (lo + hi) >> 1;
      if (lofs[mid] <= i) lo = mid; else hi = mid;
    }
    pairs[gbase[lo] + (i - lofs[lo])] = lpairs[i];
  }
}

// ---------- pass 2 (merged): per-region hist + scan -> off/dinv, counting sort -> csr_src ----------
__global__ __launch_bounds__(256) void k_region(
    const uint2* __restrict__ pairs, const int* __restrict__ rbase,
    int* __restrict__ off, float* __restrict__ dinv, int* __restrict__ csr_src) {
  __shared__ int nh[512];
  __shared__ int sofs[512];
  __shared__ int sc[256];
  __shared__ int ncur[512];
  __shared__ int cbuf[REGION_CAP];   // 40 KB

  const int r = blockIdx.x, t = threadIdx.x;
  const int base = rbase[r];
  const int cnt = rbase[r + 1] - base;

  nh[t] = 0;
  nh[t + 256] = 0;
  __syncthreads();

  for (int i = t; i < cnt; i += 256) {
    uint2 p = pairs[base + i];
    atomicAdd(&nh[p.y & 511], 1);
  }
  __syncthreads();

  // scan 512 counts with 256 threads (pairwise), keep originals in regs
  int a0 = nh[2 * t], a1 = nh[2 * t + 1];
  sc[t] = a0 + a1;
  __syncthreads();
#pragma unroll
  for (int d = 1; d < 256; d <<= 1) {
    int v = (t >= d) ? sc[t - d] : 0;
    __syncthreads();
    sc[t] += v;
    __syncthreads();
  }
  int excl = (t > 0) ? sc[t - 1] : 0;
  sofs[2 * t] = excl;
  sofs[2 * t + 1] = excl + a0;

  // write off + dinv for this region's nodes
  const int node0 = r << 9;
  int n0 = node0 + 2 * t;
  if (n0 < N_NODES)     { off[n0] = base + excl;      dinv[n0] = rsqrtf(1.f + (float)a0); }
  if (n0 + 1 < N_NODES) { off[n0 + 1] = base + excl + a0; dinv[n0 + 1] = rsqrtf(1.f + (float)a1); }
  if (r == N_REGIONS - 1 && t == 0) off[N_NODES] = N_EDGES;

  ncur[t] = 0;
  ncur[t + 256] = 0;
  __syncthreads();

  // counting sort into LDS (pairs slice is L2-hot from pass above)
  for (int i = t; i < cnt; i += 256) {
    uint2 p = pairs[base + i];
    int d = (int)p.y & 511;
    int lpos = sofs[d] + atomicAdd(&ncur[d], 1);
    if (lpos < REGION_CAP) cbuf[lpos] = (int)p.x;
  }
  __syncthreads();
  for (int i = t; i < cnt; i += 256) csr_src[base + i] = cbuf[i];
}

// ---------- MFMA GEMM: sxw_bf16 = bf16((x @ Wg) * dinv[row]) ----------
__global__ __launch_bounds__(256) void k_gemm(
    const float* __restrict__ x, const unsigned short* __restrict__ WgT,
    const float* __restrict__ dinv, unsigned short* __restrict__ sxw) {
  __shared__ unsigned short As[128][32];   // [m][k] bf16
  __shared__ unsigned short Bs[128][32];   // [n][k] bf16 (B^T)

  const int t = threadIdx.x;
  const int lane15 = t & 15;
  const int quad = (t & 63) >> 4;
  const int wave = t >> 6;
  const int wm = (wave & 1) * 64;
  const int wn = (wave >> 1) * 64;
  const int row0 = blockIdx.x * 128;

  f32x4 acc[4][4];
#pragma unroll
  for (int mi = 0; mi < 4; mi++)
#pragma unroll
    for (int ni = 0; ni < 4; ni++) acc[mi][ni] = (f32x4){0.f, 0.f, 0.f, 0.f};

  float4 ga[4];
  uint4 gb[2];
  auto load_tile = [&](int k0) {
#pragma unroll
    for (int i = 0; i < 4; i++) {
      int f = t + 256 * i;
      int r = f >> 3, c4 = f & 7;
      int gr = row0 + r;
      if (gr >= N_NODES) gr = N_NODES - 1;
      ga[i] = *(const float4*)&x[(size_t)gr * F_IN + k0 + c4 * 4];
    }
#pragma unroll
    for (int i = 0; i < 2; i++) {
      int f = t + 256 * i;
      int r = f >> 2, c = f & 3;
      gb[i] = *(const uint4*)&WgT[r * F_IN + k0 + c * 8];
    }
  };

  load_tile(0);
#pragma unroll 1
  for (int kt = 0; kt < 16; kt++) {
    __syncthreads();
#pragma unroll
    for (int i = 0; i < 4; i++) {
      int f = t + 256 * i;
      int r = f >> 3, c4 = f & 7;
      unsigned int u0 = f2bf2(ga[i].x, ga[i].y);
      unsigned int u1 = f2bf2(ga[i].z, ga[i].w);
      *(uint2*)&As[r][c4 * 4] = make_uint2(u0, u1);
    }
#pragma unroll
    for (int i = 0; i < 2; i++) {
      int f = t + 256 * i;
      int r = f >> 2, c = f & 3;
      *(uint4*)&Bs[r][c * 8] = gb[i];
    }
    __syncthreads();
    if (kt < 15) load_tile((kt + 1) * 32);

    short8 afr[4], bfr[4];
#pragma unroll
    for (int mi = 0; mi < 4; mi++)
      afr[mi] = *(const short8*)&As[wm + mi * 16 + lane15][quad * 8];
#pragma unroll
    for (int ni = 0; ni < 4; ni++)
      bfr[ni] = *(const short8*)&Bs[wn + ni * 16 + lane15][quad * 8];
#pragma unroll
    for (int mi = 0; mi < 4; mi++)
#pragma unroll
      for (int ni = 0; ni < 4; ni++)
        acc[mi][ni] = __builtin_amdgcn_mfma_f32_16x16x32_bf16(
            bfr[ni], afr[mi], acc[mi][ni], 0, 0, 0);
  }

#pragma unroll
  for (int mi = 0; mi < 4; mi++) {
    int gm = row0 + wm + mi * 16 + lane15;
    if (gm < N_NODES) {
      float s = dinv[gm];
#pragma unroll
      for (int ni = 0; ni < 4; ni++) {
        int gn = wn + ni * 16 + quad * 4;
        unsigned int u0 = f2bf2(acc[mi][ni][0] * s, acc[mi][ni][1] * s);
        unsigned int u1 = f2bf2(acc[mi][ni][2] * s, acc[mi][ni][3] * s);
        *(uint2*)&sxw[(size_t)gm * F_GNN + gn] = make_uint2(u0, u1);
      }
    }
  }
}

// ---------- fused aggregate + ReLU + mean/max pool: one block per graph ----------
__global__ __launch_bounds__(1024) void k_aggpool(
    const unsigned short* __restrict__ sxw, const int* __restrict__ off,
    const int* __restrict__ csr_src, const float* __restrict__ dinv,
    const float* __restrict__ bg, const int* __restrict__ batch,
    float* __restrict__ gx) {
  __shared__ float2 ssum[16][64];
  __shared__ float2 smax[16][64];
  __shared__ int sse[2];
  const int g = blockIdx.x;
  const int t = threadIdx.x;
  const int wv = t >> 6;
  const int lane = t & 63;

  if (t == 0) sse[0] = lower_bound_i(batch, N_NODES, g);
  if (t == 64) sse[1] = lower_bound_i(batch, N_NODES, g + 1);
  __syncthreads();
  const int start = sse[0], end = sse[1];

  const unsigned int* S = (const unsigned int*)sxw;  // 2 bf16 per uint
  float2 b = ((const float2*)bg)[lane];
  float2 ps = make_float2(0.f, 0.f);
  float2 pm = make_float2(0.f, 0.f);

  for (int node = start + wv; node < end; node += 16) {
    unsigned int u = S[(size_t)node * 64 + lane];      // self-loop
    float sx = bf_lo(u), sy = bf_hi(u);
    int e = off[node];
    int e1 = off[node + 1];
    for (; e + 7 < e1; e += 8) {
      int s0 = csr_src[e + 0], s1 = csr_src[e + 1];
      int s2 = csr_src[e + 2], s3 = csr_src[e + 3];
      int s4 = csr_src[e + 4], s5 = csr_src[e + 5];
      int s6 = csr_src[e + 6], s7 = csr_src[e + 7];
      unsigned int v0 = S[(size_t)s0 * 64 + lane];
      unsigned int v1 = S[(size_t)s1 * 64 + lane];
      unsigned int v2 = S[(size_t)s2 * 64 + lane];
      unsigned int v3 = S[(size_t)s3 * 64 + lane];
      unsigned int v4 = S[(size_t)s4 * 64 + lane];
      unsigned int v5 = S[(size_t)s5 * 64 + lane];
      unsigned int v6 = S[(size_t)s6 * 64 + lane];
      unsigned int v7 = S[(size_t)s7 * 64 + lane];
      sx += bf_lo(v0) + bf_lo(v1) + bf_lo(v2) + bf_lo(v3)
          + bf_lo(v4) + bf_lo(v5) + bf_lo(v6) + bf_lo(v7);
      sy += bf_hi(v0) + bf_hi(v1) + bf_hi(v2) + bf_hi(v3)
          + bf_hi(v4) + bf_hi(v5) + bf_hi(v6) + bf_hi(v7);
    }
    for (; e < e1; e++) {
      unsigned int v0 = S[(size_t)csr_src[e] * 64 + lane];
      sx += bf_lo(v0);
      sy += bf_hi(v0);
    }
    float di = dinv[node];
    float rx = fmaxf(fmaf(sx, di, b.x), 0.f);
    float ry = fmaxf(fmaf(sy, di, b.y), 0.f);
    ps.x += rx; ps.y += ry;
    pm.x = fmaxf(pm.x, rx); pm.y = fmaxf(pm.y, ry);
  }

  ssum[wv][lane] = ps;
  smax[wv][lane] = pm;
  __syncthreads();
  if (t < 64) {
    float2 s = ssum[0][t];
    float2 m = smax[0][t];
#pragma unroll
    for (int h = 1; h < 16; h++) {
      s.x += ssum[h][t].x; s.y += ssum[h][t].y;
      m.x = fmaxf(m.x, smax[h][t].x); m.y = fmaxf(m.y, smax[h][t].y);
    }
    float ic = 1.f / fmaxf((float)(end - start), 1.f);
    gx[g * 256 + 2 * t] = s.x * ic;
    gx[g * 256 + 2 * t + 1] = s.y * ic;
    gx[g * 256 + 128 + 2 * t] = m.x;
    gx[g * 256 + 129 + 2 * t] = m.y;
  }
}

// ---------- encoder MLP + reparam + decoder MLP ----------
__global__ __launch_bounds__(64) void k_mlp(
    const float* __restrict__ gx, const float* __restrict__ eps,
    const float* __restrict__ We1, const float* __restrict__ be1,
    const float* __restrict__ We2, const float* __restrict__ be2,
    const float* __restrict__ We3, const float* __restrict__ be3,
    const float* __restrict__ Wd1, const float* __restrict__ bd1,
    const float* __restrict__ Wd2, const float* __restrict__ bd2,
    const float* __restrict__ Wd3, const float* __restrict__ bd3,
    float* __restrict__ out) {
  __shared__ float row[256];
  __shared__ float t1[64], t2[64], zz[64], d1[64], d2[64];
  int g = blockIdx.x;
  int j = threadIdx.x;

#pragma unroll
  for (int i = 0; i < 4; i++) row[j + 64 * i] = gx[g * 256 + j + 64 * i];
  __syncthreads();

  float s = be1[j];
#pragma unroll 4
  for (int k = 0; k < 256; k++) s = fmaf(row[k], We1[k * 64 + j], s);
  t1[j] = eluf(s);
  __syncthreads();

  s = be2[j];
#pragma unroll 4
  for (int k = 0; k < 64; k++) s = fmaf(t1[k], We2[k * 64 + j], s);
  t2[j] = tanhf(s);
  __syncthreads();

  float m = be3[j], lv = be3[64 + j];
#pragma unroll 4
  for (int k = 0; k < 64; k++) {
    float tv = t2[k];
    m = fmaf(tv, We3[k * 128 + j], m);
    lv = fmaf(tv, We3[k * 128 + 64 + j], lv);
  }
  float sd = 1e-6f + softplusf(lv);
  float z = fmaf(eps[g * 64 + j], sd, m);
  out[g * 64 + j] = m;                  // mu
  out[32768 + g * 64 + j] = sd;         // stddev
  zz[j] = z;
  __syncthreads();

  s = bd1[j];
#pragma unroll 4
  for (int k = 0; k < 64; k++) s = fmaf(zz[k], Wd1[k * 64 + j], s);
  d1[j] = tanhf(s);
  __syncthreads();

  s = bd2[j];
#pragma unroll 4
  for (int k = 0; k < 64; k++) s = fmaf(d1[k], Wd2[k * 64 + j], s);
  d2[j] = eluf(s);
  __syncthreads();

  float y0 = bd3[j], y1 = bd3[64 + j];
#pragma unroll 4
  for (int k = 0; k < 64; k++) {
    float dv = d2[k];
    y0 = fmaf(dv, Wd3[k * 128 + j], y0);
    y1 = fmaf(dv, Wd3[k * 128 + 64 + j], y1);
  }
  y0 = fminf(fmaxf(sigmoidf(y0), 1e-8f), 1.f - 1e-8f);
  y1 = fminf(fmaxf(sigmoidf(y1), 1e-8f), 1.f - 1e-8f);
  out[65536 + g * 128 + j] = y0;
  out[65536 + g * 128 + 64 + j] = y1;
}

extern "C" void kernel_launch(void* const* d_in, const int* in_sizes, int n_in,
                              void* d_out, int out_size, void* d_ws, size_t ws_size,
                              hipStream_t stream) {
  const float* x     = (const float*)d_in[0];
  const int*   ei    = (const int*)d_in[1];
  const int*   batch = (const int*)d_in[2];
  const float* eps   = (const float*)d_in[3];
  const float* Wg    = (const float*)d_in[4];
  const float* bg    = (const float*)d_in[5];
  const float* We1   = (const float*)d_in[6];
  const float* be1   = (const float*)d_in[7];
  const float* We2   = (const float*)d_in[8];
  const float* be2   = (const float*)d_in[9];
  const float* We3   = (const float*)d_in[10];
  const float* be3   = (const float*)d_in[11];
  const float* Wd1   = (const float*)d_in[12];
  const float* bd1   = (const float*)d_in[13];
  const float* Wd2   = (const float*)d_in[14];
  const float* bd2   = (const float*)d_in[15];
  const float* Wd3   = (const float*)d_in[16];
  const float* bd3   = (const float*)d_in[17];
  float* out = (float*)d_out;

  // workspace layout (4B element offsets)
  int*            rbase    = (int*)d_ws;                    // 256 ints (197 used)
  int*            cursor_r = rbase + 256;                   // 256 ints (doubles as rcnt)
  int*            off      = cursor_r + 256;                // 102656 ints (100001 used)
  float*          dinv     = (float*)(off + 102656);        // 102400
  int*            csr_src  = (int*)(dinv + 102400);         // 1600128
  uint2*          pairs    = (uint2*)(csr_src + 1600128);   // 1.6M uint2 (8B aligned)
  unsigned short* WgT      = (unsigned short*)(pairs + 1600000);  // 65536 bf16
  unsigned short* sxw      = WgT + 65536;                   // 12.8M bf16
  float*          gx       = (float*)(sxw + 12800000);      // 131072 f32

  k_wg<<<(F_IN * F_GNN) / 256, 256, 0, stream>>>(Wg, WgT, cursor_r);
  k_rcount<<<(N_EDGES + 2047) / 2048, 256, 0, stream>>>(ei, cursor_r);
  k_rscan<<<1, 256, 0, stream>>>(cursor_r, rbase);
  k_bucket<<<(N_EDGES + 4095) / 4096, 256, 0, stream>>>(ei, cursor_r, pairs);
  k_region<<<N_REGIONS, 256, 0, stream>>>(pairs, rbase, off, dinv, csr_src);
  k_gemm<<<(N_NODES + 127) / 128, 256, 0, stream>>>(x, WgT, dinv, sxw);
  k_aggpool<<<N_GRAPHS, 1024, 0, stream>>>(sxw, off, csr_src, dinv, bg, batch, gx);
  k_mlp<<<N_GRAPHS, 64, 0, stream>>>(gx, eps, We1, be1, We2, be2, We3, be3,
                                     Wd1, bd1, Wd2, bd2, Wd3, bd3, out);
}